// Round 11
// baseline (43.765 us; speedup 1.0000x reference)
//
#include <hip/hip_runtime.h>

#define TILE    16
#define BLOCK   256
#define EMBED   128
#define VOCAB   50257
#define ESTRIDE 132    // emb LDS row stride (floats)
#define NPART   2048
#define NCACHE  128    // hot fc rows cached in LDS (top of Huffman tree)
#define CSTRIDE 136    // cached row stride in ushorts (272B: +16B pad, de-banks)

// ---------- pre-pass: fc fp32 -> bf16 (round-to-nearest-even) into d_ws ----
__global__ __launch_bounds__(256) void hs_pack(
    const float* __restrict__ fc, ushort* __restrict__ out, int n)
{
    const int stride = gridDim.x * 256 * 8;
    for (int i = (blockIdx.x * 256 + threadIdx.x) * 8; i < n; i += stride) {
        const uint4 a = *(const uint4*)(fc + i);
        const uint4 b = *(const uint4*)(fc + i + 4);
        ushort r[8];
        const uint* u = &a.x;
        #pragma unroll
        for (int j = 0; j < 4; ++j)
            r[j] = (ushort)((u[j] + 0x7FFFu + ((u[j] >> 16) & 1u)) >> 16);
        const uint* v = &b.x;
        #pragma unroll
        for (int j = 0; j < 4; ++j)
            r[4 + j] = (ushort)((v[j] + 0x7FFFu + ((v[j] >> 16) & 1u)) >> 16);
        *(uint4*)(out + i) = *(uint4*)r;
    }
}

// ---------- main: R5/R9 quad-per-item skeleton + LDS hot-row cache ----------
// Huffman internal nodes are numbered in merge order, so rows >= CUT are the
// shallowest ~7 levels (~41% of touches). Those rows live in LDS; deep rows
// read global bf16. d-major item order keeps the LDS/global branch nearly
// wave-uniform (all 16 quads in an iteration share one depth).
__global__ __launch_bounds__(BLOCK) void hs_main_cache(
    const float* __restrict__ emb,        // [T, 128]
    const int*   __restrict__ target,     // [T]
    const ushort* __restrict__ fcb,       // [V-1, 128] bf16
    const int*   __restrict__ path_idx,   // [V, D]
    const float* __restrict__ path_code,  // [V, D]
    const float* __restrict__ path_mask,  // [V, D]
    int T, int D, int CUT,
    float* __restrict__ partial_b,
    float* __restrict__ partial_c)
{
    extern __shared__ char smem[];
    float*  se     = (float*)smem;                            // [TILE*ESTRIDE]
    ushort* scache = (ushort*)(smem + TILE * ESTRIDE * 4);    // [NCACHE*CSTRIDE]
    int2*   sic    = (int2*)((char*)scache + NCACHE * CSTRIDE * 2); // [TILE*D]
    __shared__ float sb[BLOCK / 64];
    __shared__ float sc[BLOCK / 64];

    const int tok0 = blockIdx.x * TILE;
    const int ntok = min(TILE, T - tok0);

    // Stage emb tile (zero-fill past ntok).
    const float4* g4 = (const float4*)(emb + (size_t)tok0 * EMBED);
    for (int j = threadIdx.x; j < TILE * (EMBED / 4); j += BLOCK) {
        const int f = j * 4, tk = f >> 7, kk = f & 127;
        float4 v = make_float4(0.f, 0.f, 0.f, 0.f);
        if (tk < ntok) v = g4[j];
        *(float4*)&se[tk * ESTRIDE + kk] = v;
    }
    // Stage hot fc rows (rows CUT..CUT+NCACHE-1) into padded LDS.
    for (int s = threadIdx.x; s < NCACHE * 16; s += BLOCK) {
        const int row = s >> 4, chunk = s & 15;       // 16B chunks
        const uint4 w = *(const uint4*)(fcb + (size_t)(CUT + row) * EMBED
                                        + chunk * 8);
        *(uint4*)&scache[row * CSTRIDE + chunk * 8] = w;
    }
    // Stage path meta d-major: sic[d*TILE+tk] = {row, code} or {0,-1}.
    for (int j = threadIdx.x; j < TILE * D; j += BLOCK) {
        const int tk = j & (TILE - 1), d = j >> 4;
        int2 m = make_int2(0, __float_as_int(-1.0f));
        if (tk < ntok) {
            const int v = target[tok0 + tk];
            const size_t po = (size_t)v * D + d;
            if (path_mask[po] != 0.f)
                m = make_int2(path_idx[po], __float_as_int(path_code[po]));
        }
        sic[j] = m;
    }
    __syncthreads();

    const int wave = threadIdx.x >> 6;
    const int g    = (threadIdx.x >> 2) & 15;   // quad id == token tk
    const int sub  = threadIdx.x & 3;

    float accb = 0.f, accc = 0.f;

    const int items = TILE * D;
    for (int it = wave * 16; it < items; it += 64) {
        const int2 m = sic[it + g];
        const float code = __int_as_float(m.y);
        if (code >= 0.f) {
            uint4 w0, w1, w2, w3;
            const int row = m.x;
            if (row >= CUT) {                     // hot row: LDS (parallel pipe)
                const ushort* wr = &scache[(row - CUT) * CSTRIDE + sub * 8];
                w0 = *(const uint4*)(wr);
                w1 = *(const uint4*)(wr + 32);
                w2 = *(const uint4*)(wr + 64);
                w3 = *(const uint4*)(wr + 96);
            } else {                              // cold row: global bf16
                const ushort* wr = fcb + (size_t)row * EMBED + sub * 8;
                w0 = *(const uint4*)(wr);
                w1 = *(const uint4*)(wr + 32);
                w2 = *(const uint4*)(wr + 64);
                w3 = *(const uint4*)(wr + 96);
            }
            const float4* e4 = (const float4*)&se[g * ESTRIDE];
            float s0 = 0.f, s1 = 0.f;
            const uint4 wv[4] = {w0, w1, w2, w3};
            #pragma unroll
            for (int k = 0; k < 4; ++k) {
                const uint4  w  = wv[k];
                const float4 ea = e4[(k * 4 + sub) * 2];
                const float4 eb = e4[(k * 4 + sub) * 2 + 1];
                s0 = fmaf(ea.x, __uint_as_float(w.x << 16),         s0);
                s1 = fmaf(ea.y, __uint_as_float(w.x & 0xFFFF0000u), s1);
                s0 = fmaf(ea.z, __uint_as_float(w.y << 16),         s0);
                s1 = fmaf(ea.w, __uint_as_float(w.y & 0xFFFF0000u), s1);
                s0 = fmaf(eb.x, __uint_as_float(w.z << 16),         s0);
                s1 = fmaf(eb.y, __uint_as_float(w.z & 0xFFFF0000u), s1);
                s0 = fmaf(eb.z, __uint_as_float(w.w << 16),         s0);
                s1 = fmaf(eb.w, __uint_as_float(w.w & 0xFFFF0000u), s1);
            }
            float x = s0 + s1;
            x += __shfl_xor(x, 1);
            x += __shfl_xor(x, 2);
            accb += fmaxf(x, 0.f) - x * code + __logf(1.f + __expf(-fabsf(x)));
            accc += 1.f;                          // 4x quad overcount cancels
        }
    }

    #pragma unroll
    for (int o = 32; o > 0; o >>= 1) {
        accb += __shfl_xor(accb, o);
        accc += __shfl_xor(accc, o);
    }
    const int lane = threadIdx.x & 63;
    if (lane == 0) { sb[wave] = accb; sc[wave] = accc; }
    __syncthreads();
    if (threadIdx.x == 0) {
        float b = 0.f, c = 0.f;
        #pragma unroll
        for (int i = 0; i < BLOCK / 64; ++i) { b += sb[i]; c += sc[i]; }
        partial_b[blockIdx.x] = b;
        partial_c[blockIdx.x] = c;
    }
}

// ---------- fp32 fallback if ws too small (R5 kernel) ----------
__global__ __launch_bounds__(BLOCK) void hs_main_f32(
    const float* __restrict__ emb, const int* __restrict__ target,
    const float* __restrict__ fc,  const int* __restrict__ path_idx,
    const float* __restrict__ path_code, const float* __restrict__ path_mask,
    int T, int D, float* __restrict__ partial_b, float* __restrict__ partial_c)
{
    extern __shared__ char smem[];
    float* se  = (float*)smem;
    int2*  sic = (int2*)(smem + TILE * ESTRIDE * 4);
    __shared__ float sb[BLOCK / 64];
    __shared__ float sc[BLOCK / 64];

    const int tok0 = blockIdx.x * TILE;
    const int ntok = min(TILE, T - tok0);

    const float4* g4 = (const float4*)(emb + (size_t)tok0 * EMBED);
    for (int j = threadIdx.x; j < TILE * (EMBED / 4); j += BLOCK) {
        const int f = j * 4, tk = f >> 7, kk = f & 127;
        float4 v = make_float4(0.f, 0.f, 0.f, 0.f);
        if (tk < ntok) v = g4[j];
        *(float4*)&se[tk * ESTRIDE + kk] = v;
    }
    for (int j = threadIdx.x; j < TILE * D; j += BLOCK) {
        const int tk = j & (TILE - 1), d = j >> 4;
        int2 m = make_int2(0, __float_as_int(-1.0f));
        if (tk < ntok) {
            const int v = target[tok0 + tk];
            const size_t po = (size_t)v * D + d;
            if (path_mask[po] != 0.f)
                m = make_int2(path_idx[po], __float_as_int(path_code[po]));
        }
        sic[j] = m;
    }
    __syncthreads();

    const int wave = threadIdx.x >> 6;
    const int g    = (threadIdx.x >> 2) & 15;
    const int sub  = threadIdx.x & 3;
    float accb = 0.f, accc = 0.f;

    const int items = TILE * D;
    for (int it = wave * 16; it < items; it += 64) {
        const int2 m = sic[it + g];
        const float code = __int_as_float(m.y);
        if (code >= 0.f) {
            const float4* w4 = (const float4*)(fc + (size_t)m.x * EMBED);
            const float4* e4 = (const float4*)&se[g * ESTRIDE];
            float s0 = 0.f, s1 = 0.f, s2 = 0.f, s3 = 0.f;
            #pragma unroll
            for (int k = 0; k < 8; ++k) {
                const float4 w  = w4[k * 4 + sub];
                const float4 ev = e4[k * 4 + sub];
                s0 = fmaf(ev.x, w.x, s0); s1 = fmaf(ev.y, w.y, s1);
                s2 = fmaf(ev.z, w.z, s2); s3 = fmaf(ev.w, w.w, s3);
            }
            float x = (s0 + s1) + (s2 + s3);
            x += __shfl_xor(x, 1); x += __shfl_xor(x, 2);
            accb += fmaxf(x, 0.f) - x * code + __logf(1.f + __expf(-fabsf(x)));
            accc += 1.f;
        }
    }
    #pragma unroll
    for (int o = 32; o > 0; o >>= 1) {
        accb += __shfl_xor(accb, o);
        accc += __shfl_xor(accc, o);
    }
    const int lane = threadIdx.x & 63;
    if (lane == 0) { sb[wave] = accb; sc[wave] = accc; }
    __syncthreads();
    if (threadIdx.x == 0) {
        float b = 0.f, c = 0.f;
        #pragma unroll
        for (int i = 0; i < BLOCK / 64; ++i) { b += sb[i]; c += sc[i]; }
        partial_b[blockIdx.x] = b;
        partial_c[blockIdx.x] = c;
    }
}

// ---------- deterministic finalize ----------
__global__ __launch_bounds__(256) void hs_finalize(
    const float* __restrict__ pb, const float* __restrict__ pc,
    int n, float* __restrict__ out)
{
    __shared__ double rb[256];
    __shared__ double rc[256];
    double sbv = 0.0, scv = 0.0;
    for (int i = threadIdx.x; i < n; i += 256) {
        sbv += (double)pb[i];
        scv += (double)pc[i];
    }
    rb[threadIdx.x] = sbv; rc[threadIdx.x] = scv;
    __syncthreads();
    for (int s = 128; s > 0; s >>= 1) {
        if (threadIdx.x < s) {
            rb[threadIdx.x] += rb[threadIdx.x + s];
            rc[threadIdx.x] += rc[threadIdx.x + s];
        }
        __syncthreads();
    }
    if (threadIdx.x == 0) out[0] = (float)(rb[0] / rc[0]);
}

extern "C" void kernel_launch(void* const* d_in, const int* in_sizes, int n_in,
                              void* d_out, int out_size, void* d_ws, size_t ws_size,
                              hipStream_t stream) {
    const float* emb   = (const float*)d_in[0];
    const int*   tgt   = (const int*)  d_in[1];
    const float* fc    = (const float*)d_in[2];
    const int*   pidx  = (const int*)  d_in[3];
    const float* pcode = (const float*)d_in[4];
    const float* pmask = (const float*)d_in[5];

    const int T     = in_sizes[1];            // 32768 tokens
    const int D     = in_sizes[3] / VOCAB;    // padded max path depth
    const int nfc   = in_sizes[2];            // (V-1)*128
    const int nrows = nfc / EMBED;            // V-1
    const int CUT   = nrows > NCACHE ? nrows - NCACHE : 0;

    const int nblocks = (T + TILE - 1) / TILE;   // 2048
    const size_t shmem_cache = (size_t)TILE * ESTRIDE * 4
                             + (size_t)NCACHE * CSTRIDE * 2
                             + (size_t)TILE * D * 8;
    const size_t shmem_f32   = (size_t)TILE * ESTRIDE * 4 + (size_t)TILE * D * 8;

    float* pb = (float*)d_ws;                    // [NPART]
    float* pc = pb + NPART;                      // [NPART]
    ushort* fcb = (ushort*)((char*)d_ws + 2 * NPART * sizeof(float));
    const size_t need = 2 * NPART * sizeof(float) + (size_t)nfc * sizeof(ushort);
    float* out = (float*)d_out;

    if (ws_size >= need) {
        hs_pack<<<1024, 256, 0, stream>>>(fc, fcb, nfc);
        hs_main_cache<<<nblocks, BLOCK, shmem_cache, stream>>>(
            emb, tgt, fcb, pidx, pcode, pmask, T, D, CUT, pb, pc);
    } else {
        hs_main_f32<<<nblocks, BLOCK, shmem_f32, stream>>>(
            emb, tgt, fc, pidx, pcode, pmask, T, D, pb, pc);
    }
    hs_finalize<<<1, 256, 0, stream>>>(pb, pc, nblocks, out);
}

// Round 12
// 31.759 us; speedup vs baseline: 1.3780x; 1.3780x over previous
//
#include <hip/hip_runtime.h>

#define TILE    16
#define BLOCK   256
#define EMBED   128
#define VOCAB   50257
#define ESTRIDE 132   // 4*odd floats: spreads rows across bank-groups

// BEST MEASURED (R5, 31.9 us). 4-lane group (quad) per (token, path-node)
// item. The quad's 4 lanes read adjacent float4s of the fc row -> whole 64B
// lines per instruction (no TA amplification). emb tile + path meta staged
// in LDS once per block; d-major item order so all 16 quads of a wave share
// one depth slice (hot top-of-tree fc rows hit L1 together). Dot = 32
// in-lane FMA + 2-step intra-quad shuffle; BCE once per item; the 4x quad
// overcount cancels in the final sum/count ratio.
__global__ __launch_bounds__(BLOCK) void hs_main(
    const float* __restrict__ emb,        // [T, 128]
    const int*   __restrict__ target,     // [T]
    const float* __restrict__ fc,         // [V-1, 128]
    const int*   __restrict__ path_idx,   // [V, D]
    const float* __restrict__ path_code,  // [V, D]
    const float* __restrict__ path_mask,  // [V, D]
    int T, int D,
    float* __restrict__ partial_b,        // [gridDim.x]
    float* __restrict__ partial_c)        // [gridDim.x]
{
    extern __shared__ char smem[];
    float* se  = (float*)smem;                          // [TILE*ESTRIDE]
    int2*  sic = (int2*)(smem + TILE * ESTRIDE * 4);    // [TILE*D], d-major
    __shared__ float sb[BLOCK / 64];
    __shared__ float sc[BLOCK / 64];

    const int tok0 = blockIdx.x * TILE;
    const int ntok = min(TILE, T - tok0);

    // Stage emb tile into padded LDS (zero-fill past ntok).
    const float4* g4 = (const float4*)(emb + (size_t)tok0 * EMBED);
    for (int j = threadIdx.x; j < TILE * (EMBED / 4); j += BLOCK) {
        const int f = j * 4, tk = f >> 7, kk = f & 127;
        float4 v = make_float4(0.f, 0.f, 0.f, 0.f);
        if (tk < ntok) v = g4[j];
        *(float4*)&se[tk * ESTRIDE + kk] = v;
    }
    // Stage path meta D-MAJOR: sic[d*TILE+tk] = {row, code} or {0,-1}.
    for (int j = threadIdx.x; j < TILE * D; j += BLOCK) {
        const int tk = j & (TILE - 1), d = j >> 4;
        int2 m = make_int2(0, __float_as_int(-1.0f));
        if (tk < ntok) {
            const int v = target[tok0 + tk];
            const size_t po = (size_t)v * D + d;
            if (path_mask[po] != 0.f)
                m = make_int2(path_idx[po], __float_as_int(path_code[po]));
        }
        sic[j] = m;
    }
    __syncthreads();

    const int wave = threadIdx.x >> 6;
    const int g    = (threadIdx.x >> 2) & 15;   // quad id = token tk
    const int sub  = threadIdx.x & 3;           // sub-lane in quad

    float accb = 0.f, accc = 0.f;

    const int items = TILE * D;
    for (int it = wave * 16; it < items; it += 64) {
        const int item = it + g;                // d = it>>4 (wave-uniform)
        const int2 m = sic[item];
        const float code = __int_as_float(m.y);
        if (code >= 0.f) {                      // quad-uniform validity
            const float4* w4 = (const float4*)(fc + (size_t)m.x * EMBED);
            const float4* e4 = (const float4*)&se[g * ESTRIDE];
            float s0 = 0.f, s1 = 0.f, s2 = 0.f, s3 = 0.f;
            #pragma unroll
            for (int k = 0; k < 8; ++k) {
                const float4 w  = w4[k * 4 + sub];
                const float4 ev = e4[k * 4 + sub];
                s0 = fmaf(ev.x, w.x, s0);
                s1 = fmaf(ev.y, w.y, s1);
                s2 = fmaf(ev.z, w.z, s2);
                s3 = fmaf(ev.w, w.w, s3);
            }
            float x = (s0 + s1) + (s2 + s3);
            x += __shfl_xor(x, 1);              // reduce across the quad
            x += __shfl_xor(x, 2);
            // fast stable BCE (hw exp/log; threshold is 5.4e-2 -> plenty)
            accb += fmaxf(x, 0.f) - x * code + __logf(1.f + __expf(-fabsf(x)));
            accc += 1.f;                        // 4x overcount cancels in ratio
        }
    }

    // One reduction per block.
    #pragma unroll
    for (int o = 32; o > 0; o >>= 1) {
        accb += __shfl_xor(accb, o);
        accc += __shfl_xor(accc, o);
    }
    const int lane = threadIdx.x & 63;
    if (lane == 0) { sb[wave] = accb; sc[wave] = accc; }
    __syncthreads();
    if (threadIdx.x == 0) {
        float b = 0.f, c = 0.f;
        #pragma unroll
        for (int i = 0; i < BLOCK / 64; ++i) { b += sb[i]; c += sc[i]; }
        partial_b[blockIdx.x] = b;
        partial_c[blockIdx.x] = c;
    }
}

// Deterministic single-block finalize: double-precision sums, then divide.
__global__ __launch_bounds__(256) void hs_finalize(
    const float* __restrict__ pb,
    const float* __restrict__ pc,
    int n, float* __restrict__ out)
{
    __shared__ double rb[256];
    __shared__ double rc[256];

    double sbv = 0.0, scv = 0.0;
    for (int i = threadIdx.x; i < n; i += 256) {
        sbv += (double)pb[i];
        scv += (double)pc[i];
    }
    rb[threadIdx.x] = sbv;
    rc[threadIdx.x] = scv;
    __syncthreads();

    for (int s = 128; s > 0; s >>= 1) {
        if (threadIdx.x < s) {
            rb[threadIdx.x] += rb[threadIdx.x + s];
            rc[threadIdx.x] += rc[threadIdx.x + s];
        }
        __syncthreads();
    }
    if (threadIdx.x == 0) out[0] = (float)(rb[0] / rc[0]);
}

extern "C" void kernel_launch(void* const* d_in, const int* in_sizes, int n_in,
                              void* d_out, int out_size, void* d_ws, size_t ws_size,
                              hipStream_t stream) {
    const float* emb   = (const float*)d_in[0];
    const int*   tgt   = (const int*)  d_in[1];
    const float* fc    = (const float*)d_in[2];
    const int*   pidx  = (const int*)  d_in[3];
    const float* pcode = (const float*)d_in[4];
    const float* pmask = (const float*)d_in[5];

    const int T = in_sizes[1];            // 32768 tokens
    const int D = in_sizes[3] / VOCAB;    // padded max path depth

    const int nblocks = (T + TILE - 1) / TILE;   // 2048
    const size_t shmem = (size_t)TILE * ESTRIDE * 4 + (size_t)TILE * D * 8;

    float* pb = (float*)d_ws;
    float* pc = pb + nblocks;
    float* out = (float*)d_out;

    hs_main<<<nblocks, BLOCK, shmem, stream>>>(
        emb, tgt, fc, pidx, pcode, pmask, T, D, pb, pc);
    hs_finalize<<<1, 256, 0, stream>>>(pb, pc, nblocks, out);
}